// Round 11
// baseline (229.614 us; speedup 1.0000x reference)
//
#include <hip/hip_runtime.h>
#include <hip/hip_bf16.h>

// PatchConv2d: out[b,o,h,w] = conv3x3(x,kernel) + 0.1*(h+w)*patch_sum[b,h,w] + bias[o]
// x:(16,64,128,128) f32, kernel:(128,64,3,3) f32, bias:(128,) f32 -> out(16,128,128,128) f32
//
// R14: R11/R13 base (conv 95.4 us) with the staging INSTRUCTION STREAM
//      shrunk 4x: thread = (w-quad, ci-group-8) loads 3 rows x 8 ci as
//      float4-over-w -> 24 global_load_dwordx4 instead of 96 scalar dwords
//      (same bytes; the compiler can re-serialize a source pipeline (R13
//      null, VGPR stayed 68) but cannot undo an instruction-count cut).
//      Column sums: 4-wide per-thread partials + LDS atomicAdd into ssumL
//      (zero-init before first lgkm barrier) -- deletes the psum reduction
//      phase, keeps LDS ~50.5 KB -> 3 blocks/CU. bq ping-pong tap loop,
//      lgkm-only barriers, setprio, epilogue unchanged from the 95.4 base.
//      Tripwire: WRITE ~131 MB / FETCH ~38 MB must stay clean.

typedef __attribute__((ext_vector_type(8))) short short8;
typedef __attribute__((ext_vector_type(4))) float f32x4;

#define B_COEF 0.1f
constexpr int CI = 64, CO = 128, H = 128, W = 128;
constexpr int XPAD = 72;  // fallback-path LDS stride

static __device__ inline short bf16s(float v) {
    __hip_bfloat16 b = __float2bfloat16(v);
    return *reinterpret_cast<short*>(&b);
}

// barrier that does NOT drain vmcnt (ds ops flushed; global loads/stores fly)
static __device__ inline void bar_lgkm() {
    asm volatile("s_waitcnt lgkmcnt(0)" ::: "memory");
    __builtin_amdgcn_s_barrier();
    asm volatile("" ::: "memory");
}

// ============================ fast path ====================================

// kernel f32 [oc][ci][3][3] -> bf16 wq[tap][kc][oc][32] (ci = kc*32+j)
__global__ void prep_wq(const float* __restrict__ wgt, __hip_bfloat16* __restrict__ wq) {
    int idx = blockIdx.x * 256 + threadIdx.x;  // 9*128*64 = 73728
    if (idx < 9 * CO * CI) {
        int tap = idx >> 13;
        int rem = idx & 8191;
        int oc = rem >> 6, ci = rem & 63;
        int kc = ci >> 5, j = ci & 31;
        wq[(((tap * 2 + kc) * CO + oc) << 5) + j] =
            __float2bfloat16(wgt[(oc * CI + ci) * 9 + tap]);
    }
}

// One output row (full W) per block: fused NCHW->NHWC-bf16 staging + conv.
__global__ __launch_bounds__(256, 3)
void conv_fused(const float* __restrict__ x,
                const __hip_bfloat16* __restrict__ wq,
                const float* __restrict__ bias,
                float* __restrict__ out) {
    __shared__ __hip_bfloat16 xrow[3][130 * 64];  // 49,920 B, swizzled units
    __shared__ float ssumL[130];

    const int tid = threadIdx.x, bx = blockIdx.x, b = blockIdx.y;
    // XCD-coherent remap: xcd = bx&7 owns h in [xcd*16, xcd*16+16)
    const int h = ((bx & 7) << 4) | (bx >> 3);
    const int lane = tid & 63, waveid = tid >> 6;
    const int lo16 = lane & 15, quad = lane >> 4;
    const int m0 = (waveid & 1) * 64, n0 = (waveid >> 1) * 64;

    // ---- staging decomposition: thread = (w-quad wq4, ci-group cg of 8)
    const int wq4 = (tid & 31) * 4;  // w base (0,4,...,124)
    const int cg = tid >> 5;         // ci group 0..7 (8 ci each)
    const float* xb = x + (size_t)b * CI * H * W;

    // issue all 24 float4 loads first (vmcnt; fly under the init + barrier)
    f32x4 vr[3][8];
#pragma unroll
    for (int r = 0; r < 3; ++r) {
        const int gh = h - 1 + r;
        if ((unsigned)gh < (unsigned)H) {
            const float* px = xb + ((size_t)(cg * 8) * H + gh) * W + wq4;
#pragma unroll
            for (int j = 0; j < 8; ++j)
                vr[r][j] = *(const f32x4*)(px + (size_t)j * (H * W));
        } else {
#pragma unroll
            for (int j = 0; j < 8; ++j) vr[r][j] = f32x4{0.0f, 0.0f, 0.0f, 0.0f};
        }
    }

    // ---- init (off critical path): halo-zero columns + ssumL zeros
    if (tid < 48) {
        const int r = tid >> 4, s = ((tid >> 3) & 1) ? 129 : 0, u = tid & 7;
        short8 z = {0, 0, 0, 0, 0, 0, 0, 0};
        *(short8*)&xrow[r][s * 64 + ((u ^ (s & 7)) * 8)] = z;
    }
    if (tid < 130) ssumL[tid] = 0.0f;
    bar_lgkm();  // ds-init visible; global loads still in flight

    // ---- pack + swizzled ds_write + 4-wide column partials
    f32x4 sacc4 = {0.0f, 0.0f, 0.0f, 0.0f};
#pragma unroll
    for (int r = 0; r < 3; ++r) {
#pragma unroll
        for (int i = 0; i < 4; ++i) {
            const int s = wq4 + i + 1;
            short8 pk;
#pragma unroll
            for (int j = 0; j < 8; ++j) pk[j] = bf16s(vr[r][j][i]);
            *(short8*)&xrow[r][s * 64 + ((cg ^ (s & 7)) * 8)] = pk;
        }
#pragma unroll
        for (int j = 0; j < 8; ++j) sacc4 += vr[r][j];
    }
#pragma unroll
    for (int i = 0; i < 4; ++i)
        atomicAdd(&ssumL[wq4 + i + 1], sacc4[i]);

    // ---- tap-0 B-frags: issued after staging; fly across the barrier
    short8 bq[2][2][4];  // [pingpong][kc][ni]
#pragma unroll
    for (int kc = 0; kc < 2; ++kc)
#pragma unroll
        for (int ni = 0; ni < 4; ++ni)
            bq[0][kc][ni] = *(const short8*)(
                wq + ((kc * CO + n0 + ni * 16 + lo16) << 5) + quad * 8);

    bar_lgkm();  // xrow + ssumL complete

    // ---- MFMA phase: tap-flattened loop, bq ping-pong prefetch
    f32x4 acc[4][4] = {};

    __builtin_amdgcn_s_setprio(1);
#pragma unroll
    for (int tap = 0; tap < 9; ++tap) {
        const int pp = tap & 1;
        // prefetch next tap's B-frags; MFMA below waits only on bq[pp]
        if (tap < 8) {
            const int tn = tap + 1;
#pragma unroll
            for (int kc = 0; kc < 2; ++kc)
#pragma unroll
                for (int ni = 0; ni < 4; ++ni)
                    bq[pp ^ 1][kc][ni] = *(const short8*)(
                        wq + (((tn * 2 + kc) * CO + n0 + ni * 16 + lo16) << 5) + quad * 8);
        }
        const int kh = tap / 3, kw = tap - kh * 3;
        const __hip_bfloat16* xs = &xrow[kh][0];
#pragma unroll
        for (int kc = 0; kc < 2; ++kc) {
            short8 af[4];
#pragma unroll
            for (int mi = 0; mi < 4; ++mi) {
                const int row = m0 + mi * 16 + lo16 + kw;
                af[mi] = *(const short8*)
                    &xs[row * 64 + (((kc * 4 + quad) ^ (row & 7)) * 8)];
            }
#pragma unroll
            for (int mi = 0; mi < 4; ++mi)
#pragma unroll
                for (int ni = 0; ni < 4; ++ni)
                    acc[mi][ni] = __builtin_amdgcn_mfma_f32_16x16x32_bf16(
                        af[mi], bq[pp][kc][ni], acc[mi][ni], 0, 0, 0);
        }
    }
    __builtin_amdgcn_s_setprio(0);

    // ---- epilogue: + 0.1*(h+w)*patch_sum + bias; float4 stores (fire & fly)
#pragma unroll
    for (int mi = 0; mi < 4; ++mi) {
        const int wbase = m0 + mi * 16 + quad * 4;
        float cs[6];
#pragma unroll
        for (int t = 0; t < 6; ++t) cs[t] = ssumL[wbase + t];
        float ps[4], cf[4];
#pragma unroll
        for (int t = 0; t < 4; ++t) {
            ps[t] = cs[t] + cs[t + 1] + cs[t + 2];
            cf[t] = B_COEF * (float)(h + wbase + t);
        }
#pragma unroll
        for (int ni = 0; ni < 4; ++ni) {
            const int oc = n0 + ni * 16 + lo16;
            const float bv = bias[oc];
            f32x4 v = acc[mi][ni];
#pragma unroll
            for (int t = 0; t < 4; ++t) v[t] = v[t] + cf[t] * ps[t] + bv;
            *(f32x4*)(out + (((size_t)b * CO + oc) * H + h) * W + wbase) = v;
        }
    }
}

// ===================== fallback path (R2, needs only 147 KB ws) ============

constexpr int WPAD = 72;

__global__ void prep_w_fb(const float* __restrict__ wgt, __hip_bfloat16* __restrict__ wt) {
    int idx = blockIdx.x * 256 + threadIdx.x;
    if (idx < 9 * CO * CI) {
        int tap = idx / (CO * CI);
        int rem = idx - tap * (CO * CI);
        int oc = rem >> 6, ci = rem & 63;
        wt[idx] = __float2bfloat16(wgt[(oc * CI + ci) * 9 + tap]);
    }
}

__global__ __launch_bounds__(256, 2)
void conv_fb(const float* __restrict__ x, const __hip_bfloat16* __restrict__ wt,
             const float* __restrict__ bias, float* __restrict__ out) {
    __shared__ __hip_bfloat16 xrow[130 * XPAD];
    __shared__ __hip_bfloat16 wlds[CO * WPAD];
    __shared__ float colsum[132];

    const int tid = threadIdx.x;
    const int h = blockIdx.x, b = blockIdx.y;
    const int lane = tid & 63, waveid = tid >> 6;
    const int lo16 = lane & 15, quad = lane >> 4;
    const int m0 = (waveid & 1) * 64, n0 = (waveid >> 1) * 64;

    f32x4 acc[4][4] = {};
    if (tid < 132) colsum[tid] = 0.0f;
    const float* xb = x + (size_t)b * CI * H * W;

    const int w16 = tid & 15, cipl = (tid >> 4) & 3, rest0 = tid >> 6;

    for (int kh = 0; kh < 3; ++kh) {
        const int gh = h - 1 + kh;
        __syncthreads();
        for (int it = 0; it < 18; ++it) {
            int rest = rest0 + it * 4;
            int whi = rest % 9, ciph = rest / 9;
            int w = whi * 16 + w16;
            int ci0 = (ciph * 4 + cipl) * 2;
            int gw = w - 1;
            float x0 = 0.0f, x1 = 0.0f;
            if (w < 130 && gw >= 0 && gw < W && gh >= 0 && gh < H) {
                const float* p = xb + (size_t)ci0 * (H * W) + gh * W + gw;
                x0 = p[0];
                x1 = p[H * W];
            }
            if (w < 130) {
                __hip_bfloat162 pk;
                pk.x = __float2bfloat16(x0);
                pk.y = __float2bfloat16(x1);
                *(__hip_bfloat162*)&xrow[w * XPAD + ci0] = pk;
            }
            float cs = x0 + x1;
            cs += __shfl_xor(cs, 16);
            cs += __shfl_xor(cs, 32);
            if (quad == 0 && w < 130) atomicAdd(&colsum[w], cs);
        }
        for (int kw = 0; kw < 3; ++kw) {
            __syncthreads();
            {
                const __hip_bfloat16* wtap = wt + (kh * 3 + kw) * (CO * CI);
#pragma unroll
                for (int it = 0; it < 4; ++it) {
                    int j = tid + it * 256;
                    int oc = j >> 3, ch = (j & 7) * 8;
                    short8 v = *(const short8*)(wtap + oc * CI + ch);
                    *(short8*)&wlds[oc * WPAD + ch] = v;
                }
            }
            __syncthreads();
#pragma unroll
            for (int kc = 0; kc < 2; ++kc) {
                const int krow = kc * 32 + quad * 8;
                short8 af[4], bf[4];
#pragma unroll
                for (int mi = 0; mi < 4; ++mi)
                    af[mi] = *(const short8*)&xrow[(m0 + mi * 16 + lo16 + kw) * XPAD + krow];
#pragma unroll
                for (int ni = 0; ni < 4; ++ni)
                    bf[ni] = *(const short8*)&wlds[(n0 + ni * 16 + lo16) * WPAD + krow];
#pragma unroll
                for (int mi = 0; mi < 4; ++mi)
#pragma unroll
                    for (int ni = 0; ni < 4; ++ni)
                        acc[mi][ni] = __builtin_amdgcn_mfma_f32_16x16x32_bf16(
                            af[mi], bf[ni], acc[mi][ni], 0, 0, 0);
            }
        }
    }
    __syncthreads();
#pragma unroll
    for (int mi = 0; mi < 4; ++mi) {
        const int wbase = m0 + mi * 16 + quad * 4;
        float cs[6];
#pragma unroll
        for (int r = 0; r < 6; ++r) cs[r] = colsum[wbase + r];
        float ps[4], cf[4];
#pragma unroll
        for (int r = 0; r < 4; ++r) {
            ps[r] = cs[r] + cs[r + 1] + cs[r + 2];
            cf[r] = B_COEF * (float)(h + wbase + r);
        }
#pragma unroll
        for (int ni = 0; ni < 4; ++ni) {
            const int oc = n0 + ni * 16 + lo16;
            const float bv = bias[oc];
            f32x4 v = acc[mi][ni];
#pragma unroll
            for (int r = 0; r < 4; ++r) v[r] = v[r] + cf[r] * ps[r] + bv;
            *(f32x4*)(out + (((size_t)b * CO + oc) * H + h) * W + wbase) = v;
        }
    }
}

// ===========================================================================

extern "C" void kernel_launch(void* const* d_in, const int* in_sizes, int n_in,
                              void* d_out, int out_size, void* d_ws, size_t ws_size,
                              hipStream_t stream) {
    const float* x    = (const float*)d_in[0];
    const float* wgt  = (const float*)d_in[1];
    const float* bias = (const float*)d_in[2];
    float* out = (float*)d_out;

    const size_t WQ_BYTES = (size_t)9 * 2 * CO * 32 * 2;  // 147,456

    if (ws_size >= WQ_BYTES) {
        __hip_bfloat16* wq = (__hip_bfloat16*)d_ws;
        prep_wq<<<dim3(288), dim3(256), 0, stream>>>(wgt, wq);
        conv_fused<<<dim3(H, 16), dim3(256), 0, stream>>>(x, wq, bias, out);
    } else {
        __hip_bfloat16* wt = (__hip_bfloat16*)d_ws;  // 147,456 B
        prep_w_fb<<<dim3(288), dim3(256), 0, stream>>>(wgt, wt);
        conv_fb<<<dim3(H, 16), dim3(256), 0, stream>>>(x, wt, bias, out);
    }
}

// Round 12
// 221.015 us; speedup vs baseline: 1.0389x; 1.0389x over previous
//
#include <hip/hip_runtime.h>
#include <hip/hip_bf16.h>

// PatchConv2d: out[b,o,h,w] = conv3x3(x,kernel) + 0.1*(h+w)*patch_sum[b,h,w] + bias[o]
// x:(16,64,128,128) f32, kernel:(128,64,3,3) f32, bias:(128,) f32 -> out(16,128,128,128) f32
//
// R15: R11 base (95.4 us, proven staging w/ 0 bank conflicts) + two L2-
//      traffic cuts:
//  (1) DISJOINT wave->oc mapping: n0 = waveid*32, each wave computes all
//      128 w for its 32 oc. Waves 0/1 and 2/3 previously loaded IDENTICAL
//      bq data (same n0); now the block reads wq exactly once (144 KB vs
//      288 KB) -> bq L2 stream halves (590->295 MB), MFMA-phase VMEM instrs
//      drop 72->36 per wave. MFMA/ds_read/store counts unchanged.
//      acc[8][2]=64 AGPR; af held 4-at-a-time -> peak ~130 VGPR, no spill.
//  (2) Non-temporal epilogue stores: out is streamed once, never re-read --
//      keeps 134 MB out of L2.
//      R14's conflicted staging reverted (bank conflicts 2.36M -> 0).

typedef __attribute__((ext_vector_type(8))) short short8;
typedef __attribute__((ext_vector_type(4))) float f32x4;

#define B_COEF 0.1f
constexpr int CI = 64, CO = 128, H = 128, W = 128;
constexpr int XPAD = 72;  // fallback-path LDS stride

static __device__ inline short bf16s(float v) {
    __hip_bfloat16 b = __float2bfloat16(v);
    return *reinterpret_cast<short*>(&b);
}

// barrier that does NOT drain vmcnt (ds ops flushed; global loads/stores fly)
static __device__ inline void bar_lgkm() {
    asm volatile("s_waitcnt lgkmcnt(0)" ::: "memory");
    __builtin_amdgcn_s_barrier();
    asm volatile("" ::: "memory");
}

// ============================ fast path ====================================

// kernel f32 [oc][ci][3][3] -> bf16 wq[tap][kc][oc][32] (ci = kc*32+j)
__global__ void prep_wq(const float* __restrict__ wgt, __hip_bfloat16* __restrict__ wq) {
    int idx = blockIdx.x * 256 + threadIdx.x;  // 9*128*64 = 73728
    if (idx < 9 * CO * CI) {
        int tap = idx >> 13;
        int rem = idx & 8191;
        int oc = rem >> 6, ci = rem & 63;
        int kc = ci >> 5, j = ci & 31;
        wq[(((tap * 2 + kc) * CO + oc) << 5) + j] =
            __float2bfloat16(wgt[(oc * CI + ci) * 9 + tap]);
    }
}

// One output row (full W) per block: fused NCHW->NHWC-bf16 staging + conv.
__global__ __launch_bounds__(256, 3)
void conv_fused(const float* __restrict__ x,
                const __hip_bfloat16* __restrict__ wq,
                const float* __restrict__ bias,
                float* __restrict__ out) {
    __shared__ __hip_bfloat16 xrow[3][130 * 64];  // 49,920 B, swizzled units
    __shared__ float psum[256];
    __shared__ float ssumL[130];

    const int tid = threadIdx.x, bx = blockIdx.x, b = blockIdx.y;
    // XCD-coherent remap: xcd = bx&7 owns h in [xcd*16, xcd*16+16)
    const int h = ((bx & 7) << 4) | (bx >> 3);
    const int lane = tid & 63, waveid = tid >> 6;
    const int lo16 = lane & 15, quad = lane >> 4;
    const int n0 = waveid * 32;  // disjoint 32-oc slice per wave, all 128 w

    // ---- tap-0 B-frags: issued first (oldest vmcnt; complete under staging)
    short8 bq[2][2][2];  // [pingpong][kc][ni]
#pragma unroll
    for (int kc = 0; kc < 2; ++kc)
#pragma unroll
        for (int ni = 0; ni < 2; ++ni)
            bq[0][kc][ni] = *(const short8*)(
                wq + ((kc * CO + n0 + ni * 16 + lo16) << 5) + quad * 8);

    // ---- zero the two always-pad halo columns (slots 0 and 129)
    if (tid < 48) {
        const int r = tid >> 4, s = ((tid >> 3) & 1) ? 129 : 0, u = tid & 7;
        short8 z = {0, 0, 0, 0, 0, 0, 0, 0};
        *(short8*)&xrow[r][s * 64 + ((u ^ (s & 7)) * 8)] = z;
    }

    // ---- staged transpose (R11-proven, 0 conflicts): thread = (w, ci-half);
    //      12 iters of {8 coalesced dword loads, cvt+pack, swizzled b128 write}
    const int wl = tid & 127, cg0 = tid >> 7;
    const int wslot = wl + 1, wsw = wslot & 7;
    float sacc = 0.0f;
    const float* xb = x + (size_t)b * CI * H * W + wl;
#pragma unroll
    for (int p = 0; p < 4; ++p) {
        const int cg = cg0 + 2 * p;
#pragma unroll
        for (int r = 0; r < 3; ++r) {
            const int gh = h - 1 + r;
            short8 pk = {0, 0, 0, 0, 0, 0, 0, 0};
            if (gh >= 0 && gh < H) {
                const float* px = xb + ((size_t)(cg * 8) * H + gh) * W;
                float v[8];
#pragma unroll
                for (int j = 0; j < 8; ++j) v[j] = px[(size_t)j * H * W];
#pragma unroll
                for (int j = 0; j < 8; ++j) {
                    pk[j] = bf16s(v[j]);
                    sacc += v[j];
                }
            }
            *(short8*)&xrow[r][wslot * 64 + ((cg ^ wsw) * 8)] = pk;
        }
    }
    psum[tid] = sacc;
    bar_lgkm();

    // ---- column sums (patch_sum precursor, already 3-row summed)
    if (tid < 128) ssumL[tid + 1] = psum[tid] + psum[tid + 128];
    if (tid == 128) ssumL[0] = 0.0f;
    if (tid == 129) ssumL[129] = 0.0f;
    bar_lgkm();

    // ---- MFMA phase: tap-flattened loop, bq ping-pong prefetch.
    //      Wave covers all 8 m-fragments x 2 n-fragments for its oc slice.
    f32x4 acc[8][2] = {};

    __builtin_amdgcn_s_setprio(1);
#pragma unroll
    for (int tap = 0; tap < 9; ++tap) {
        const int pp = tap & 1;
        // prefetch next tap's B-frags; MFMA below waits only on bq[pp]
        if (tap < 8) {
            const int tn = tap + 1;
#pragma unroll
            for (int kc = 0; kc < 2; ++kc)
#pragma unroll
                for (int ni = 0; ni < 2; ++ni)
                    bq[pp ^ 1][kc][ni] = *(const short8*)(
                        wq + (((tn * 2 + kc) * CO + n0 + ni * 16 + lo16) << 5) + quad * 8);
        }
        const int kh = tap / 3, kw = tap - kh * 3;
        const __hip_bfloat16* xs = &xrow[kh][0];
#pragma unroll
        for (int kc = 0; kc < 2; ++kc) {
#pragma unroll
            for (int mig = 0; mig < 2; ++mig) {  // af held 4-at-a-time
                short8 af[4];
#pragma unroll
                for (int q = 0; q < 4; ++q) {
                    const int row = (mig * 4 + q) * 16 + lo16 + kw;
                    af[q] = *(const short8*)
                        &xs[row * 64 + (((kc * 4 + quad) ^ (row & 7)) * 8)];
                }
#pragma unroll
                for (int q = 0; q < 4; ++q)
#pragma unroll
                    for (int ni = 0; ni < 2; ++ni)
                        acc[mig * 4 + q][ni] = __builtin_amdgcn_mfma_f32_16x16x32_bf16(
                            af[q], bq[pp][kc][ni], acc[mig * 4 + q][ni], 0, 0, 0);
            }
        }
    }
    __builtin_amdgcn_s_setprio(0);

    // ---- epilogue: + 0.1*(h+w)*patch_sum + bias; non-temporal f32x4 stores
#pragma unroll
    for (int mi = 0; mi < 8; ++mi) {
        const int wbase = mi * 16 + quad * 4;
        float cs[6];
#pragma unroll
        for (int t = 0; t < 6; ++t) cs[t] = ssumL[wbase + t];
        float ps[4], cf[4];
#pragma unroll
        for (int t = 0; t < 4; ++t) {
            ps[t] = cs[t] + cs[t + 1] + cs[t + 2];
            cf[t] = B_COEF * (float)(h + wbase + t);
        }
#pragma unroll
        for (int ni = 0; ni < 2; ++ni) {
            const int oc = n0 + ni * 16 + lo16;
            const float bv = bias[oc];
            f32x4 v = acc[mi][ni];
#pragma unroll
            for (int t = 0; t < 4; ++t) v[t] = v[t] + cf[t] * ps[t] + bv;
            __builtin_nontemporal_store(
                v, (f32x4*)(out + (((size_t)b * CO + oc) * H + h) * W + wbase));
        }
    }
}

// ===================== fallback path (R2, needs only 147 KB ws) ============

constexpr int WPAD = 72;

__global__ void prep_w_fb(const float* __restrict__ wgt, __hip_bfloat16* __restrict__ wt) {
    int idx = blockIdx.x * 256 + threadIdx.x;
    if (idx < 9 * CO * CI) {
        int tap = idx / (CO * CI);
        int rem = idx - tap * (CO * CI);
        int oc = rem >> 6, ci = rem & 63;
        wt[idx] = __float2bfloat16(wgt[(oc * CI + ci) * 9 + tap]);
    }
}

__global__ __launch_bounds__(256, 2)
void conv_fb(const float* __restrict__ x, const __hip_bfloat16* __restrict__ wt,
             const float* __restrict__ bias, float* __restrict__ out) {
    __shared__ __hip_bfloat16 xrow[130 * XPAD];
    __shared__ __hip_bfloat16 wlds[CO * WPAD];
    __shared__ float colsum[132];

    const int tid = threadIdx.x;
    const int h = blockIdx.x, b = blockIdx.y;
    const int lane = tid & 63, waveid = tid >> 6;
    const int lo16 = lane & 15, quad = lane >> 4;
    const int m0 = (waveid & 1) * 64, n0 = (waveid >> 1) * 64;

    f32x4 acc[4][4] = {};
    if (tid < 132) colsum[tid] = 0.0f;
    const float* xb = x + (size_t)b * CI * H * W;

    const int w16 = tid & 15, cipl = (tid >> 4) & 3, rest0 = tid >> 6;

    for (int kh = 0; kh < 3; ++kh) {
        const int gh = h - 1 + kh;
        __syncthreads();
        for (int it = 0; it < 18; ++it) {
            int rest = rest0 + it * 4;
            int whi = rest % 9, ciph = rest / 9;
            int w = whi * 16 + w16;
            int ci0 = (ciph * 4 + cipl) * 2;
            int gw = w - 1;
            float x0 = 0.0f, x1 = 0.0f;
            if (w < 130 && gw >= 0 && gw < W && gh >= 0 && gh < H) {
                const float* p = xb + (size_t)ci0 * (H * W) + gh * W + gw;
                x0 = p[0];
                x1 = p[H * W];
            }
            if (w < 130) {
                __hip_bfloat162 pk;
                pk.x = __float2bfloat16(x0);
                pk.y = __float2bfloat16(x1);
                *(__hip_bfloat162*)&xrow[w * XPAD + ci0] = pk;
            }
            float cs = x0 + x1;
            cs += __shfl_xor(cs, 16);
            cs += __shfl_xor(cs, 32);
            if (quad == 0 && w < 130) atomicAdd(&colsum[w], cs);
        }
        for (int kw = 0; kw < 3; ++kw) {
            __syncthreads();
            {
                const __hip_bfloat16* wtap = wt + (kh * 3 + kw) * (CO * CI);
#pragma unroll
                for (int it = 0; it < 4; ++it) {
                    int j = tid + it * 256;
                    int oc = j >> 3, ch = (j & 7) * 8;
                    short8 v = *(const short8*)(wtap + oc * CI + ch);
                    *(short8*)&wlds[oc * WPAD + ch] = v;
                }
            }
            __syncthreads();
#pragma unroll
            for (int kc = 0; kc < 2; ++kc) {
                const int krow = kc * 32 + quad * 8;
                short8 af[4], bf[4];
#pragma unroll
                for (int mi = 0; mi < 4; ++mi)
                    af[mi] = *(const short8*)&xrow[(m0 + mi * 16 + lo16 + kw) * XPAD + krow];
#pragma unroll
                for (int ni = 0; ni < 4; ++ni)
                    bf[ni] = *(const short8*)&wlds[(n0 + ni * 16 + lo16) * WPAD + krow];
#pragma unroll
                for (int mi = 0; mi < 4; ++mi)
#pragma unroll
                    for (int ni = 0; ni < 4; ++ni)
                        acc[mi][ni] = __builtin_amdgcn_mfma_f32_16x16x32_bf16(
                            af[mi], bf[ni], acc[mi][ni], 0, 0, 0);
            }
        }
    }
    __syncthreads();
#pragma unroll
    for (int mi = 0; mi < 4; ++mi) {
        const int wbase = m0 + mi * 16 + quad * 4;
        float cs[6];
#pragma unroll
        for (int r = 0; r < 6; ++r) cs[r] = colsum[wbase + r];
        float ps[4], cf[4];
#pragma unroll
        for (int r = 0; r < 4; ++r) {
            ps[r] = cs[r] + cs[r + 1] + cs[r + 2];
            cf[r] = B_COEF * (float)(h + wbase + r);
        }
#pragma unroll
        for (int ni = 0; ni < 4; ++ni) {
            const int oc = n0 + ni * 16 + lo16;
            const float bv = bias[oc];
            f32x4 v = acc[mi][ni];
#pragma unroll
            for (int r = 0; r < 4; ++r) v[r] = v[r] + cf[r] * ps[r] + bv;
            *(f32x4*)(out + (((size_t)b * CO + oc) * H + h) * W + wbase) = v;
        }
    }
}

// ===========================================================================

extern "C" void kernel_launch(void* const* d_in, const int* in_sizes, int n_in,
                              void* d_out, int out_size, void* d_ws, size_t ws_size,
                              hipStream_t stream) {
    const float* x    = (const float*)d_in[0];
    const float* wgt  = (const float*)d_in[1];
    const float* bias = (const float*)d_in[2];
    float* out = (float*)d_out;

    const size_t WQ_BYTES = (size_t)9 * 2 * CO * 32 * 2;  // 147,456

    if (ws_size >= WQ_BYTES) {
        __hip_bfloat16* wq = (__hip_bfloat16*)d_ws;
        prep_wq<<<dim3(288), dim3(256), 0, stream>>>(wgt, wq);
        conv_fused<<<dim3(H, 16), dim3(256), 0, stream>>>(x, wq, bias, out);
    } else {
        __hip_bfloat16* wt = (__hip_bfloat16*)d_ws;  // 147,456 B
        prep_w_fb<<<dim3(288), dim3(256), 0, stream>>>(wgt, wt);
        conv_fb<<<dim3(H, 16), dim3(256), 0, stream>>>(x, wt, bias, out);
    }
}

// Round 13
// 219.313 us; speedup vs baseline: 1.0470x; 1.0078x over previous
//
#include <hip/hip_runtime.h>
#include <hip/hip_bf16.h>

// PatchConv2d: out[b,o,h,w] = conv3x3(x,kernel) + 0.1*(h+w)*patch_sum[b,h,w] + bias[o]
// x:(16,64,128,128) f32, kernel:(128,64,3,3) f32, bias:(128,) f32 -> out(16,128,128,128) f32
//
// R16: R15 (86.6 us, best) with ONE change: non-temporal epilogue stores
//      removed. R15's WRITE_SIZE jumped 131->180 MB: nt bypasses L2 write-
//      combining, so 64 B store segments reached HBM unmerged (~4/3 write
//      amplification, ~7 us of wasted HBM time). Plain stores restore L2
//      line merging (each oc-row's 512 B written by 8 same-wave instrs).
//      Disjoint wave->oc mapping (the real R15 win, ~+16 us) is kept:
//      n0 = waveid*32, block reads wq exactly once, bq ping-pong prefetch,
//      lgkm-only barriers, proven 0-conflict staging.

typedef __attribute__((ext_vector_type(8))) short short8;
typedef __attribute__((ext_vector_type(4))) float f32x4;

#define B_COEF 0.1f
constexpr int CI = 64, CO = 128, H = 128, W = 128;
constexpr int XPAD = 72;  // fallback-path LDS stride

static __device__ inline short bf16s(float v) {
    __hip_bfloat16 b = __float2bfloat16(v);
    return *reinterpret_cast<short*>(&b);
}

// barrier that does NOT drain vmcnt (ds ops flushed; global loads/stores fly)
static __device__ inline void bar_lgkm() {
    asm volatile("s_waitcnt lgkmcnt(0)" ::: "memory");
    __builtin_amdgcn_s_barrier();
    asm volatile("" ::: "memory");
}

// ============================ fast path ====================================

// kernel f32 [oc][ci][3][3] -> bf16 wq[tap][kc][oc][32] (ci = kc*32+j)
__global__ void prep_wq(const float* __restrict__ wgt, __hip_bfloat16* __restrict__ wq) {
    int idx = blockIdx.x * 256 + threadIdx.x;  // 9*128*64 = 73728
    if (idx < 9 * CO * CI) {
        int tap = idx >> 13;
        int rem = idx & 8191;
        int oc = rem >> 6, ci = rem & 63;
        int kc = ci >> 5, j = ci & 31;
        wq[(((tap * 2 + kc) * CO + oc) << 5) + j] =
            __float2bfloat16(wgt[(oc * CI + ci) * 9 + tap]);
    }
}

// One output row (full W) per block: fused NCHW->NHWC-bf16 staging + conv.
__global__ __launch_bounds__(256, 3)
void conv_fused(const float* __restrict__ x,
                const __hip_bfloat16* __restrict__ wq,
                const float* __restrict__ bias,
                float* __restrict__ out) {
    __shared__ __hip_bfloat16 xrow[3][130 * 64];  // 49,920 B, swizzled units
    __shared__ float psum[256];
    __shared__ float ssumL[130];

    const int tid = threadIdx.x, bx = blockIdx.x, b = blockIdx.y;
    // XCD-coherent remap: xcd = bx&7 owns h in [xcd*16, xcd*16+16)
    const int h = ((bx & 7) << 4) | (bx >> 3);
    const int lane = tid & 63, waveid = tid >> 6;
    const int lo16 = lane & 15, quad = lane >> 4;
    const int n0 = waveid * 32;  // disjoint 32-oc slice per wave, all 128 w

    // ---- tap-0 B-frags: issued first (oldest vmcnt; complete under staging)
    short8 bq[2][2][2];  // [pingpong][kc][ni]
#pragma unroll
    for (int kc = 0; kc < 2; ++kc)
#pragma unroll
        for (int ni = 0; ni < 2; ++ni)
            bq[0][kc][ni] = *(const short8*)(
                wq + ((kc * CO + n0 + ni * 16 + lo16) << 5) + quad * 8);

    // ---- zero the two always-pad halo columns (slots 0 and 129)
    if (tid < 48) {
        const int r = tid >> 4, s = ((tid >> 3) & 1) ? 129 : 0, u = tid & 7;
        short8 z = {0, 0, 0, 0, 0, 0, 0, 0};
        *(short8*)&xrow[r][s * 64 + ((u ^ (s & 7)) * 8)] = z;
    }

    // ---- staged transpose (R11-proven, 0 conflicts): thread = (w, ci-half);
    //      12 iters of {8 coalesced dword loads, cvt+pack, swizzled b128 write}
    const int wl = tid & 127, cg0 = tid >> 7;
    const int wslot = wl + 1, wsw = wslot & 7;
    float sacc = 0.0f;
    const float* xb = x + (size_t)b * CI * H * W + wl;
#pragma unroll
    for (int p = 0; p < 4; ++p) {
        const int cg = cg0 + 2 * p;
#pragma unroll
        for (int r = 0; r < 3; ++r) {
            const int gh = h - 1 + r;
            short8 pk = {0, 0, 0, 0, 0, 0, 0, 0};
            if (gh >= 0 && gh < H) {
                const float* px = xb + ((size_t)(cg * 8) * H + gh) * W;
                float v[8];
#pragma unroll
                for (int j = 0; j < 8; ++j) v[j] = px[(size_t)j * H * W];
#pragma unroll
                for (int j = 0; j < 8; ++j) {
                    pk[j] = bf16s(v[j]);
                    sacc += v[j];
                }
            }
            *(short8*)&xrow[r][wslot * 64 + ((cg ^ wsw) * 8)] = pk;
        }
    }
    psum[tid] = sacc;
    bar_lgkm();

    // ---- column sums (patch_sum precursor, already 3-row summed)
    if (tid < 128) ssumL[tid + 1] = psum[tid] + psum[tid + 128];
    if (tid == 128) ssumL[0] = 0.0f;
    if (tid == 129) ssumL[129] = 0.0f;
    bar_lgkm();

    // ---- MFMA phase: tap-flattened loop, bq ping-pong prefetch.
    //      Wave covers all 8 m-fragments x 2 n-fragments for its oc slice.
    f32x4 acc[8][2] = {};

    __builtin_amdgcn_s_setprio(1);
#pragma unroll
    for (int tap = 0; tap < 9; ++tap) {
        const int pp = tap & 1;
        // prefetch next tap's B-frags; MFMA below waits only on bq[pp]
        if (tap < 8) {
            const int tn = tap + 1;
#pragma unroll
            for (int kc = 0; kc < 2; ++kc)
#pragma unroll
                for (int ni = 0; ni < 2; ++ni)
                    bq[pp ^ 1][kc][ni] = *(const short8*)(
                        wq + (((tn * 2 + kc) * CO + n0 + ni * 16 + lo16) << 5) + quad * 8);
        }
        const int kh = tap / 3, kw = tap - kh * 3;
        const __hip_bfloat16* xs = &xrow[kh][0];
#pragma unroll
        for (int kc = 0; kc < 2; ++kc) {
#pragma unroll
            for (int mig = 0; mig < 2; ++mig) {  // af held 4-at-a-time
                short8 af[4];
#pragma unroll
                for (int q = 0; q < 4; ++q) {
                    const int row = (mig * 4 + q) * 16 + lo16 + kw;
                    af[q] = *(const short8*)
                        &xs[row * 64 + (((kc * 4 + quad) ^ (row & 7)) * 8)];
                }
#pragma unroll
                for (int q = 0; q < 4; ++q)
#pragma unroll
                    for (int ni = 0; ni < 2; ++ni)
                        acc[mig * 4 + q][ni] = __builtin_amdgcn_mfma_f32_16x16x32_bf16(
                            af[q], bq[pp][kc][ni], acc[mig * 4 + q][ni], 0, 0, 0);
            }
        }
    }
    __builtin_amdgcn_s_setprio(0);

    // ---- epilogue: + 0.1*(h+w)*patch_sum + bias; plain f32x4 stores
    //      (L2 write-combining merges the 8 per-row segments into full lines)
#pragma unroll
    for (int mi = 0; mi < 8; ++mi) {
        const int wbase = mi * 16 + quad * 4;
        float cs[6];
#pragma unroll
        for (int t = 0; t < 6; ++t) cs[t] = ssumL[wbase + t];
        float ps[4], cf[4];
#pragma unroll
        for (int t = 0; t < 4; ++t) {
            ps[t] = cs[t] + cs[t + 1] + cs[t + 2];
            cf[t] = B_COEF * (float)(h + wbase + t);
        }
#pragma unroll
        for (int ni = 0; ni < 2; ++ni) {
            const int oc = n0 + ni * 16 + lo16;
            const float bv = bias[oc];
            f32x4 v = acc[mi][ni];
#pragma unroll
            for (int t = 0; t < 4; ++t) v[t] = v[t] + cf[t] * ps[t] + bv;
            *(f32x4*)(out + (((size_t)b * CO + oc) * H + h) * W + wbase) = v;
        }
    }
}

// ===================== fallback path (R2, needs only 147 KB ws) ============

constexpr int WPAD = 72;

__global__ void prep_w_fb(const float* __restrict__ wgt, __hip_bfloat16* __restrict__ wt) {
    int idx = blockIdx.x * 256 + threadIdx.x;
    if (idx < 9 * CO * CI) {
        int tap = idx / (CO * CI);
        int rem = idx - tap * (CO * CI);
        int oc = rem >> 6, ci = rem & 63;
        wt[idx] = __float2bfloat16(wgt[(oc * CI + ci) * 9 + tap]);
    }
}

__global__ __launch_bounds__(256, 2)
void conv_fb(const float* __restrict__ x, const __hip_bfloat16* __restrict__ wt,
             const float* __restrict__ bias, float* __restrict__ out) {
    __shared__ __hip_bfloat16 xrow[130 * XPAD];
    __shared__ __hip_bfloat16 wlds[CO * WPAD];
    __shared__ float colsum[132];

    const int tid = threadIdx.x;
    const int h = blockIdx.x, b = blockIdx.y;
    const int lane = tid & 63, waveid = tid >> 6;
    const int lo16 = lane & 15, quad = lane >> 4;
    const int m0 = (waveid & 1) * 64, n0 = (waveid >> 1) * 64;

    f32x4 acc[4][4] = {};
    if (tid < 132) colsum[tid] = 0.0f;
    const float* xb = x + (size_t)b * CI * H * W;

    const int w16 = tid & 15, cipl = (tid >> 4) & 3, rest0 = tid >> 6;

    for (int kh = 0; kh < 3; ++kh) {
        const int gh = h - 1 + kh;
        __syncthreads();
        for (int it = 0; it < 18; ++it) {
            int rest = rest0 + it * 4;
            int whi = rest % 9, ciph = rest / 9;
            int w = whi * 16 + w16;
            int ci0 = (ciph * 4 + cipl) * 2;
            int gw = w - 1;
            float x0 = 0.0f, x1 = 0.0f;
            if (w < 130 && gw >= 0 && gw < W && gh >= 0 && gh < H) {
                const float* p = xb + (size_t)ci0 * (H * W) + gh * W + gw;
                x0 = p[0];
                x1 = p[H * W];
            }
            if (w < 130) {
                __hip_bfloat162 pk;
                pk.x = __float2bfloat16(x0);
                pk.y = __float2bfloat16(x1);
                *(__hip_bfloat162*)&xrow[w * XPAD + ci0] = pk;
            }
            float cs = x0 + x1;
            cs += __shfl_xor(cs, 16);
            cs += __shfl_xor(cs, 32);
            if (quad == 0 && w < 130) atomicAdd(&colsum[w], cs);
        }
        for (int kw = 0; kw < 3; ++kw) {
            __syncthreads();
            {
                const __hip_bfloat16* wtap = wt + (kh * 3 + kw) * (CO * CI);
#pragma unroll
                for (int it = 0; it < 4; ++it) {
                    int j = tid + it * 256;
                    int oc = j >> 3, ch = (j & 7) * 8;
                    short8 v = *(const short8*)(wtap + oc * CI + ch);
                    *(short8*)&wlds[oc * WPAD + ch] = v;
                }
            }
            __syncthreads();
#pragma unroll
            for (int kc = 0; kc < 2; ++kc) {
                const int krow = kc * 32 + quad * 8;
                short8 af[4], bf[4];
#pragma unroll
                for (int mi = 0; mi < 4; ++mi)
                    af[mi] = *(const short8*)&xrow[(m0 + mi * 16 + lo16 + kw) * XPAD + krow];
#pragma unroll
                for (int ni = 0; ni < 4; ++ni)
                    bf[ni] = *(const short8*)&wlds[(n0 + ni * 16 + lo16) * WPAD + krow];
#pragma unroll
                for (int mi = 0; mi < 4; ++mi)
#pragma unroll
                    for (int ni = 0; ni < 4; ++ni)
                        acc[mi][ni] = __builtin_amdgcn_mfma_f32_16x16x32_bf16(
                            af[mi], bf[ni], acc[mi][ni], 0, 0, 0);
            }
        }
    }
    __syncthreads();
#pragma unroll
    for (int mi = 0; mi < 4; ++mi) {
        const int wbase = m0 + mi * 16 + quad * 4;
        float cs[6];
#pragma unroll
        for (int r = 0; r < 6; ++r) cs[r] = colsum[wbase + r];
        float ps[4], cf[4];
#pragma unroll
        for (int r = 0; r < 4; ++r) {
            ps[r] = cs[r] + cs[r + 1] + cs[r + 2];
            cf[r] = B_COEF * (float)(h + wbase + r);
        }
#pragma unroll
        for (int ni = 0; ni < 4; ++ni) {
            const int oc = n0 + ni * 16 + lo16;
            const float bv = bias[oc];
            f32x4 v = acc[mi][ni];
#pragma unroll
            for (int r = 0; r < 4; ++r) v[r] = v[r] + cf[r] * ps[r] + bv;
            *(f32x4*)(out + (((size_t)b * CO + oc) * H + h) * W + wbase) = v;
        }
    }
}

// ===========================================================================

extern "C" void kernel_launch(void* const* d_in, const int* in_sizes, int n_in,
                              void* d_out, int out_size, void* d_ws, size_t ws_size,
                              hipStream_t stream) {
    const float* x    = (const float*)d_in[0];
    const float* wgt  = (const float*)d_in[1];
    const float* bias = (const float*)d_in[2];
    float* out = (float*)d_out;

    const size_t WQ_BYTES = (size_t)9 * 2 * CO * 32 * 2;  // 147,456

    if (ws_size >= WQ_BYTES) {
        __hip_bfloat16* wq = (__hip_bfloat16*)d_ws;
        prep_wq<<<dim3(288), dim3(256), 0, stream>>>(wgt, wq);
        conv_fused<<<dim3(H, 16), dim3(256), 0, stream>>>(x, wq, bias, out);
    } else {
        __hip_bfloat16* wt = (__hip_bfloat16*)d_ws;  // 147,456 B
        prep_w_fb<<<dim3(288), dim3(256), 0, stream>>>(wgt, wt);
        conv_fb<<<dim3(H, 16), dim3(256), 0, stream>>>(x, wt, bias, out);
    }
}